// Round 3
// baseline (12.712 us; speedup 1.0000x reference)
//
#include <hip/hip_runtime.h>
#include <math.h>

typedef __attribute__((ext_vector_type(8))) short bf16x8;
typedef __attribute__((ext_vector_type(4))) float f32x4;

#define TPB  512
#define NBLK 256

// LDS byte offsets (all 16B-aligned).
#define W1T_OFF 0                       // [128 n][136 k] bf16, stride 272B
#define W2T_OFF 34816                   // [64  n][136 k] bf16, stride 272B
#define W3T_OFF 52224                   // [32  n][72  k] bf16, stride 144B
#define SCR_OFF 56832                   // per-tower-wave [16][136] bf16 scratch
#define SCR_PW  4352                    // 4 tower waves
#define PG_OFF  74240                   // [4 tw][16 row][4 g] f32 gmf partials
#define SM_BYTES (PG_OFF + 1024)        // 75264 B -> 1 block/CU, 8 waves

__device__ __forceinline__ unsigned short f2bf(float a){
  unsigned ua = __float_as_uint(a);
  return (unsigned short)((ua + 0x7FFFu + ((ua>>16)&1u)) >> 16);   // RNE
}
__device__ __forceinline__ unsigned int f2bf_pk(float a, float b){
  return (unsigned int)f2bf(a) | ((unsigned int)f2bf(b) << 16);
}
__device__ __forceinline__ bf16x8 mk_frag(float4 a, float4 ba, float4 b, float4 bb){
  union { bf16x8 v; unsigned int u[4]; } o;
  o.u[0] = f2bf_pk(fmaxf(a.x+ba.x,0.f), fmaxf(a.y+ba.y,0.f));
  o.u[1] = f2bf_pk(fmaxf(a.z+ba.z,0.f), fmaxf(a.w+ba.w,0.f));
  o.u[2] = f2bf_pk(fmaxf(b.x+bb.x,0.f), fmaxf(b.y+bb.y,0.f));
  o.u[3] = f2bf_pk(fmaxf(b.z+bb.z,0.f), fmaxf(b.w+bb.w,0.f));
  return o.v;
}

__launch_bounds__(TPB, 2)
__global__ void ncf_mfma(
    const int* __restrict__ user, const int* __restrict__ item,
    const float* __restrict__ Wug, const float* __restrict__ bug,
    const float* __restrict__ Wum, const float* __restrict__ bum,
    const float* __restrict__ Wig, const float* __restrict__ big,
    const float* __restrict__ Wim, const float* __restrict__ bim,
    const float* __restrict__ W1, const float* __restrict__ b1,
    const float* __restrict__ W2, const float* __restrict__ b2,
    const float* __restrict__ W3, const float* __restrict__ b3,
    const float* __restrict__ Wp, const float* __restrict__ bp,
    float* __restrict__ out)
{
  extern __shared__ __align__(16) char sm[];
  const int t    = threadIdx.x;
  const int lane = t & 63;
  const int w    = t >> 6;           // 0..7
  const int r    = lane & 15;
  const int g    = lane >> 4;
  const bool twv = (w < 4);          // tower wave?
  const int  tw  = twv ? w : (w - 4);
  const int  gb  = blockIdx.x * 64 + tw * 16 + r;

  // ---- issue gathers early (role-dependent, wave-uniform branch) ----
  float4 mu0, mu1, mu2, mu3, mi0, mi1, mi2, mi3;
  float4 bu0, bu1, bu2, bu3, bi0, bi1, bi2, bi3;
  float  b1v[8], b2v[4], b3v[2], wp3[2], bpv = 0.f;
  float4 ga[4], gi[4], gba[4], gbb[4], wpv[4];

  if (twv) {
    const int u  = user[gb];
    const int it = item[gb];
    const float* up = Wum + (size_t)u  * 64;
    const float* ip = Wim + (size_t)it * 64;
    mu0 = *(const float4*)(up + 8*g);       mu1 = *(const float4*)(up + 8*g + 4);
    mu2 = *(const float4*)(up + 32 + 8*g);  mu3 = *(const float4*)(up + 32 + 8*g + 4);
    mi0 = *(const float4*)(ip + 8*g);       mi1 = *(const float4*)(ip + 8*g + 4);
    mi2 = *(const float4*)(ip + 32 + 8*g);  mi3 = *(const float4*)(ip + 32 + 8*g + 4);
    bu0 = *(const float4*)(bum + 8*g);      bu1 = *(const float4*)(bum + 8*g + 4);
    bu2 = *(const float4*)(bum + 32 + 8*g); bu3 = *(const float4*)(bum + 32 + 8*g + 4);
    bi0 = *(const float4*)(bim + 8*g);      bi1 = *(const float4*)(bim + 8*g + 4);
    bi2 = *(const float4*)(bim + 32 + 8*g); bi3 = *(const float4*)(bim + 32 + 8*g + 4);
    #pragma unroll
    for (int i = 0; i < 8; ++i) b1v[i] = b1[i*16 + r];
    #pragma unroll
    for (int i = 0; i < 4; ++i) b2v[i] = b2[i*16 + r];
    #pragma unroll
    for (int i = 0; i < 2; ++i) { b3v[i] = b3[i*16 + r]; wp3[i] = Wp[64 + i*16 + r]; }
    bpv = bp[0];
  } else {
    const int u  = user[gb];
    const int it = item[gb];
    const float* ugp = Wug + (size_t)u  * 64 + 16*g;
    const float* igp = Wig + (size_t)it * 64 + 16*g;
    #pragma unroll
    for (int c = 0; c < 4; ++c) {
      ga[c]  = *(const float4*)(ugp + 4*c);
      gi[c]  = *(const float4*)(igp + 4*c);
      gba[c] = *(const float4*)(bug + 16*g + 4*c);
      gbb[c] = *(const float4*)(big + 16*g + 4*c);
      wpv[c] = *(const float4*)(Wp  + 16*g + 4*c);
    }
  }

  // ---- stage weights -> LDS bf16 [n][k] (all 8 waves split the work) ----
  #pragma unroll
  for (int i = 0; i < 16; ++i) {                 // W1: 8192 u32 words
    int p = i*TPB + t; int n = p & 127, kp = p >> 7;
    float f0 = W1[(2*kp)*128 + n], f1 = W1[(2*kp+1)*128 + n];
    *(unsigned int*)(sm + W1T_OFF + n*272 + kp*4) = f2bf_pk(f0, f1);
  }
  #pragma unroll
  for (int i = 0; i < 8; ++i) {                  // W2: 4096 words
    int p = i*TPB + t; int n = p & 63, kp = p >> 6;
    float f0 = W2[(2*kp)*64 + n], f1 = W2[(2*kp+1)*64 + n];
    *(unsigned int*)(sm + W2T_OFF + n*272 + kp*4) = f2bf_pk(f0, f1);
  }
  #pragma unroll
  for (int i = 0; i < 2; ++i) {                  // W3: 1024 words
    int p = i*TPB + t; int n = p & 31, kp = p >> 5;
    float f0 = W3[(2*kp)*32 + n], f1 = W3[(2*kp+1)*32 + n];
    *(unsigned int*)(sm + W3T_OFF + n*144 + kp*4) = f2bf_pk(f0, f1);
  }

  bf16x8 afr[4];
  if (twv) {
    // layer-1 A fragments straight from the gather
    afr[0] = mk_frag(mu0, bu0, mu1, bu1);
    afr[1] = mk_frag(mu2, bu2, mu3, bu3);
    afr[2] = mk_frag(mi0, bi0, mi1, bi1);
    afr[3] = mk_frag(mi2, bi2, mi3, bi3);
  } else {
    // GMF (pure f32, exact): partial over this lane's 16 cols
    float psum = 0.f;
    #pragma unroll
    for (int c = 0; c < 4; ++c) {
      psum += fmaxf(ga[c].x+gba[c].x,0.f) * fmaxf(gi[c].x+gbb[c].x,0.f) * wpv[c].x;
      psum += fmaxf(ga[c].y+gba[c].y,0.f) * fmaxf(gi[c].y+gbb[c].y,0.f) * wpv[c].y;
      psum += fmaxf(ga[c].z+gba[c].z,0.f) * fmaxf(gi[c].z+gbb[c].z,0.f) * wpv[c].z;
      psum += fmaxf(ga[c].w+gba[c].w,0.f) * fmaxf(gi[c].w+gbb[c].w,0.f) * wpv[c].w;
    }
    ((float*)(sm + PG_OFF))[tw*64 + r*4 + g] = psum;
  }

  __syncthreads();   // s1: weights staged, gmf partials written

  if (twv) {
    char* scr = sm + SCR_OFF + tw * SCR_PW;   // wave-private scratch

    // ---- layer 1: [16,128] @ [128,128] ----
    #pragma unroll
    for (int nt = 0; nt < 8; ++nt) {
      f32x4 acc = {b1v[nt], b1v[nt], b1v[nt], b1v[nt]};
      #pragma unroll
      for (int s = 0; s < 4; ++s) {
        bf16x8 bf = *(const bf16x8*)(sm + W1T_OFF + (nt*16 + r)*272 + s*64 + g*16);
        acc = __builtin_amdgcn_mfma_f32_16x16x32_bf16(afr[s], bf, acc, 0, 0, 0);
      }
      #pragma unroll
      for (int q = 0; q < 4; ++q)
        *(unsigned short*)(scr + (4*g + q)*272 + (nt*16 + r)*2) = f2bf(fmaxf(acc[q], 0.f));
    }

    // ---- layer 2: [16,128] @ [128,64] ----
    bf16x8 a2[4];
    #pragma unroll
    for (int s = 0; s < 4; ++s)
      a2[s] = *(const bf16x8*)(scr + r*272 + s*64 + g*16);
    #pragma unroll
    for (int nt = 0; nt < 4; ++nt) {
      f32x4 acc = {b2v[nt], b2v[nt], b2v[nt], b2v[nt]};
      #pragma unroll
      for (int s = 0; s < 4; ++s) {
        bf16x8 bf = *(const bf16x8*)(sm + W2T_OFF + (nt*16 + r)*272 + s*64 + g*16);
        acc = __builtin_amdgcn_mfma_f32_16x16x32_bf16(a2[s], bf, acc, 0, 0, 0);
      }
      #pragma unroll
      for (int q = 0; q < 4; ++q)
        *(unsigned short*)(scr + (4*g + q)*144 + (nt*16 + r)*2) = f2bf(fmaxf(acc[q], 0.f));
    }

    // ---- layer 3: [16,64] @ [64,32] ----
    bf16x8 a3[2];
    #pragma unroll
    for (int s = 0; s < 2; ++s)
      a3[s] = *(const bf16x8*)(scr + r*144 + s*64 + g*16);
    float h3p[4] = {0.f, 0.f, 0.f, 0.f};
    #pragma unroll
    for (int nt = 0; nt < 2; ++nt) {
      f32x4 acc = {b3v[nt], b3v[nt], b3v[nt], b3v[nt]};
      #pragma unroll
      for (int s = 0; s < 2; ++s) {
        bf16x8 bf = *(const bf16x8*)(sm + W3T_OFF + (nt*16 + r)*144 + s*64 + g*16);
        acc = __builtin_amdgcn_mfma_f32_16x16x32_bf16(a3[s], bf, acc, 0, 0, 0);
      }
      #pragma unroll
      for (int q = 0; q < 4; ++q)
        h3p[q] += fmaxf(acc[q], 0.f) * wp3[nt];
    }

    // h3 col-partials -> f32 scratch [16 rows][20]
    float* scf = (float*)scr;
    #pragma unroll
    for (int q = 0; q < 4; ++q) scf[(4*g + q)*20 + r] = h3p[q];
  }

  __syncthreads();   // s2: h3 partials + gmf partials visible

  if (twv && lane < 16) {
    const float* scf = (const float*)(sm + SCR_OFF + tw * SCR_PW);
    const float4* row = (const float4*)(scf + lane*20);
    const float4* pg  = (const float4*)((const float*)(sm + PG_OFF) + tw*64 + lane*4);
    float x = bpv;
    #pragma unroll
    for (int i = 0; i < 4; ++i) { float4 v = row[i]; x += v.x + v.y + v.z + v.w; }
    { float4 v = pg[0]; x += v.x + v.y + v.z + v.w; }
    out[blockIdx.x*64 + tw*16 + lane] = 1.f / (1.f + expf(-x));
  }
}

extern "C" void kernel_launch(void* const* d_in, const int* in_sizes, int n_in,
                              void* d_out, int out_size, void* d_ws, size_t ws_size,
                              hipStream_t stream) {
  const int*   user = (const int*)  d_in[0];
  const int*   item = (const int*)  d_in[1];
  const float* Wug  = (const float*)d_in[2];
  const float* bug  = (const float*)d_in[3];
  const float* Wum  = (const float*)d_in[4];
  const float* bum  = (const float*)d_in[5];
  const float* Wig  = (const float*)d_in[6];
  const float* big  = (const float*)d_in[7];
  const float* Wim  = (const float*)d_in[8];
  const float* bim  = (const float*)d_in[9];
  const float* W1   = (const float*)d_in[10];
  const float* b1   = (const float*)d_in[11];
  const float* W2   = (const float*)d_in[12];
  const float* b2   = (const float*)d_in[13];
  const float* W3   = (const float*)d_in[14];
  const float* b3   = (const float*)d_in[15];
  const float* Wp   = (const float*)d_in[16];
  const float* bp   = (const float*)d_in[17];
  float* out = (float*)d_out;

  (void)hipFuncSetAttribute(reinterpret_cast<const void*>(ncf_mfma),
                            hipFuncAttributeMaxDynamicSharedMemorySize, SM_BYTES);
  ncf_mfma<<<NBLK, TPB, SM_BYTES, stream>>>(
      user, item, Wug, bug, Wum, bum, Wig, big, Wim, bim,
      W1, b1, W2, b2, W3, b3, Wp, bp, out);
}